// Round 3
// baseline (949.434 us; speedup 1.0000x reference)
//
#include <hip/hip_runtime.h>
#include <cstdint>

// MoE grouped-GEMM pipeline for MI355X (gfx950).
//   T=4096 tokens, D=1024, H=5632, experts 0..3 active (4..7 masked), top-2.
// R5 == R3 resubmit (GPU unavailable 3 rounds; twice re-audited, no changes):
//     256x128-tile, 8-wave, BK=32, TRIPLE-buffered LDS, 2-sub-phase-per-K-tile
//     counted-vmcnt pipeline (T3+T4), XOR LDS swizzle (T2, conflict-free b128
//     frag reads), s_setprio around MFMA (T5). gemm1 fused dual-B (w1,w3).
// Workspace layout (bytes), total 240,681,024 (yb aliases w1b, dead after gemm1):
//   xb 0 | w1b/yb 8388608 | w3b 54525952 | w2b 100663296 | hb 146800640 (8320 rows pad)
//   cnt 240517120 | offs 240517152 | perm 240517184 | wgt 240582720 | code 240648256

#define T_TOK 4096
#define DIM   1024
#define HID   5632
#define EA    4
#define NT1   32     // gemm1 K-tiles: 1024/32
#define NT2   176    // gemm2 K-tiles: 5632/32

typedef __bf16 bf16x8 __attribute__((ext_vector_type(8)));
typedef float  f32x4  __attribute__((ext_vector_type(4)));

__device__ __forceinline__ unsigned short f2b(float f) {
  union { float f; uint32_t u; } v; v.f = f;
  uint32_t r = v.u + 0x7fffu + ((v.u >> 16) & 1u);   // RNE, matches HW cvt
  return (unsigned short)(r >> 16);
}
__device__ __forceinline__ float b2f(unsigned short u) {
  union { uint32_t u; float f; } v; v.u = ((uint32_t)u) << 16;
  return v.f;
}
// async global->LDS, 16B per lane; LDS dest = wave-uniform base + lane*16
__device__ __forceinline__ void async16(const void* g, void* l) {
  __builtin_amdgcn_global_load_lds((const __attribute__((address_space(1))) void*)g,
                                   (__attribute__((address_space(3))) void*)l,
                                   16, 0, 0);
}
// raw sync primitives: keep prefetch loads in flight across the barrier
__device__ __forceinline__ void bar_raw()   { asm volatile("s_barrier" ::: "memory"); }
__device__ __forceinline__ void wait_vm4()  { asm volatile("s_waitcnt vmcnt(4)" ::: "memory"); }
__device__ __forceinline__ void wait_vm3()  { asm volatile("s_waitcnt vmcnt(3)" ::: "memory"); }
__device__ __forceinline__ void wait_vm0()  { asm volatile("s_waitcnt vmcnt(0)" ::: "memory"); }
__device__ __forceinline__ void wait_lgkm0(){ asm volatile("s_waitcnt lgkmcnt(0)" ::: "memory"); }

// LDS tile swizzle: logical byte L in a [rows][32 bf16] region (64B rows),
// phys = L ^ ((row&7)<<4)  with row = L>>6, i.e. p4^=L6, p5^=L7, p6^=L8.
// Read side: frag offset ^= (lane&7)<<4 (row bits 0-2 == lane bits 0-2).
// Stage side uses the inverse (phys slot -> logical element); 16B-block-preserving.
__device__ __forceinline__ int inv_swz(int p) {
  const int b6 = (p >> 6) & 1, b7 = (p >> 7) & 1, b8 = (p >> 8) & 1;
  return p ^ (((b6 ^ b8) << 4) | (b7 << 5) | (b8 << 6));
}

// ---------------- x fp32 -> bf16 ----------------
__global__ void cvtx_kernel(const float* __restrict__ x, unsigned short* __restrict__ xb) {
  const int i = blockIdx.x * blockDim.x + threadIdx.x;
  const float4 v = ((const float4*)x)[i];
  ushort4 o;
  o.x = f2b(v.x); o.y = f2b(v.y); o.z = f2b(v.z); o.w = f2b(v.w);
  ((ushort4*)xb)[i] = o;
}

// ---------------- gating: fp32 logits (experts 0..3), top-2, route ----------------
__global__ void gate_kernel(const float* __restrict__ x, const float* __restrict__ gw,
                            int* __restrict__ cnt, int* __restrict__ perm,
                            float* __restrict__ wgt, int* __restrict__ code) {
  const int lane = threadIdx.x & 63;
  const int wave = threadIdx.x >> 6;
  const int t = blockIdx.x * 4 + wave;          // one wave per token
  const float4* xv = (const float4*)(x + (size_t)t * DIM);
  const float4* g0 = (const float4*)gw;
  const float4* g1 = (const float4*)(gw + DIM);
  const float4* g2 = (const float4*)(gw + 2 * DIM);
  const float4* g3 = (const float4*)(gw + 3 * DIM);
  float a0 = 0.f, a1 = 0.f, a2 = 0.f, a3 = 0.f;
#pragma unroll
  for (int i = 0; i < 4; i++) {
    const int idx = i * 64 + lane;
    const float4 v = xv[idx];
    float4 w;
    w = g0[idx]; a0 += v.x*w.x + v.y*w.y + v.z*w.z + v.w*w.w;
    w = g1[idx]; a1 += v.x*w.x + v.y*w.y + v.z*w.z + v.w*w.w;
    w = g2[idx]; a2 += v.x*w.x + v.y*w.y + v.z*w.z + v.w*w.w;
    w = g3[idx]; a3 += v.x*w.x + v.y*w.y + v.z*w.z + v.w*w.w;
  }
#pragma unroll
  for (int off = 32; off > 0; off >>= 1) {
    a0 += __shfl_xor(a0, off);
    a1 += __shfl_xor(a1, off);
    a2 += __shfl_xor(a2, off);
    a3 += __shfl_xor(a3, off);
  }
  if (lane == 0) {
    float l[4] = {a0, a1, a2, a3};
    int a = 0;
#pragma unroll
    for (int e = 1; e < 4; e++) if (l[e] > l[a]) a = e;   // ties -> lower index (jax top_k)
    int b = (a == 0) ? 1 : 0;
#pragma unroll
    for (int e = 0; e < 4; e++) if (e != a && l[e] > l[b]) b = e;
    // softmax(top2) renormalized == sigmoid of logit gap
    const float wa = 1.0f / (1.0f + __expf(l[b] - l[a]));
    const float wb = 1.0f - wa;
    const int pa = atomicAdd(&cnt[a], 1);
    const int pb = atomicAdd(&cnt[b], 1);
    perm[a * T_TOK + pa] = t;  wgt[a * T_TOK + pa] = wa;  code[t * 2 + 0] = a * T_TOK + pa;
    perm[b * T_TOK + pb] = t;  wgt[b * T_TOK + pb] = wb;  code[t * 2 + 1] = b * T_TOK + pb;
  }
}

__global__ void offsets_kernel(const int* __restrict__ cnt, int* __restrict__ offs) {
  if (threadIdx.x == 0 && blockIdx.x == 0) {
    int s = 0;
#pragma unroll
    for (int e = 0; e < EA; e++) { offs[e] = s; s += cnt[e]; }
  }
}

// ---------------- per-expert transpose + fp32->bf16: in [R][C] -> out [C][R] ----------------
__global__ void tcvt_kernel(const float* __restrict__ in, unsigned short* __restrict__ out,
                            int R, int C) {
  __shared__ float tile[64][65];
  const size_t es = (size_t)R * C;
  const float* ip = in + (size_t)blockIdx.z * es;
  unsigned short* op = out + (size_t)blockIdx.z * es;
  const int bc = blockIdx.x * 64;
  const int br = blockIdx.y * 64;
  const int tr = threadIdx.x >> 4;
  const int tc = (threadIdx.x & 15) * 4;
#pragma unroll
  for (int i = 0; i < 4; i++) {
    const float4 v = *(const float4*)(ip + (size_t)(br + tr + i * 16) * C + bc + tc);
    tile[tr + i * 16][tc + 0] = v.x;
    tile[tr + i * 16][tc + 1] = v.y;
    tile[tr + i * 16][tc + 2] = v.z;
    tile[tr + i * 16][tc + 3] = v.w;
  }
  __syncthreads();
#pragma unroll
  for (int i = 0; i < 4; i++) {
    const int n = bc + tr + i * 16;
    ushort4 o;
    o.x = f2b(tile[tc + 0][tr + i * 16]);
    o.y = f2b(tile[tc + 1][tr + i * 16]);
    o.z = f2b(tile[tc + 2][tr + i * 16]);
    o.w = f2b(tile[tc + 3][tr + i * 16]);
    *(ushort4*)(op + (size_t)n * R + br + tc) = o;
  }
}

// ---------------- GEMM1: h = silu(x@w1) * (x@w3) ----------------
// Tile 256M x 128N, BK=32, 8 waves (4M x 2N), per-wave 64x64 per matrix.
// Triple-buffered LDS (3 x [A 16KB | B1 8KB | B3 8KB] = 96KB), swizzled.
// Grid 2816: nb fastest (44), e (4), mb (16); same-(e,nb) stride 176 % 8 == 0.
__global__ __launch_bounds__(512, 2)
void gemm1_kernel(const unsigned short* __restrict__ xb,
                  const unsigned short* __restrict__ w1b,
                  const unsigned short* __restrict__ w3b,
                  unsigned short* __restrict__ hb,
                  const int* __restrict__ cnt, const int* __restrict__ offs,
                  const int* __restrict__ perm) {
  const int id = blockIdx.x;
  const int nb = id % 44;
  const int e  = (id / 44) % 4;
  const int mb = id / 176;
  const int Me = cnt[e];
  const int m0 = mb * 256;
  if (m0 >= Me) return;
  const int n0 = nb * 128;
  const int goff = offs[e];
  const int tid = threadIdx.x, lane = tid & 63, wave = tid >> 6;
  const int wm = wave >> 1, wn = wave & 1;
  const int fm = lane & 15;

  __shared__ __align__(16) char smem[3 * 32768];

  // ---- staging source pointers (per-thread fixed row/k, advance 32 shorts/K-tile)
  const int pA0 = tid * 16, pA1 = 8192 + tid * 16, pB = tid * 16;
  const int lA0 = inv_swz(pA0), lA1 = inv_swz(pA1), lB = inv_swz(pB);
  const int arow0 = lA0 >> 6, ks0 = (lA0 & 63) >> 1;
  const int arow1 = lA1 >> 6, ks1 = (lA1 & 63) >> 1;
  const int brow  = lB  >> 6, ksb = (lB  & 63) >> 1;
  const int tok0 = perm[e * T_TOK + min(m0 + arow0, Me - 1)];
  const int tok1 = perm[e * T_TOK + min(m0 + arow1, Me - 1)];
  const unsigned short* ap0 = xb + (size_t)tok0 * DIM + ks0;
  const unsigned short* ap1 = xb + (size_t)tok1 * DIM + ks1;
  const unsigned short* b1p = w1b + ((size_t)e * HID + n0 + brow) * DIM + ksb;
  const unsigned short* b3p = w3b + ((size_t)e * HID + n0 + brow) * DIM + ksb;

  // ---- LDS stage dests (wave-uniform; HW adds lane*16)
  const int dA0 = wave * 1024, dA1 = 8192 + wave * 1024;
  const int dB1 = 16384 + wave * 1024, dB3 = 24576 + wave * 1024;

  // ---- swizzled frag read offsets (within region; mi/ni add *1024, clean of XOR bits)
  const int X = (lane & 7) << 4;
  const int aoff = (((wm * 64 + fm) * 64) + ((lane >> 4) * 16)) ^ X;
  const int boff = (((wn * 64 + fm) * 64) + ((lane >> 4) * 16)) ^ X;

  f32x4 acc1[4][4] = {};
  f32x4 acc3[4][4] = {};

  // ---- prologue: stage kt0 -> buf0, kt1 -> buf1 (8 loads/thread in flight)
  {
    char* D = smem;
    async16(ap0, D + dA0); async16(ap1, D + dA1);
    async16(b1p, D + dB1); async16(b3p, D + dB3);
    ap0 += 32; ap1 += 32; b1p += 32; b3p += 32;
    D = smem + 32768;
    async16(ap0, D + dA0); async16(ap1, D + dA1);
    async16(b1p, D + dB1); async16(b3p, D + dB3);
    ap0 += 32; ap1 += 32; b1p += 32; b3p += 32;
  }
  wait_vm4();               // kt0 landed; kt1 (4 loads) still in flight
  bar_raw();

  int cb = 0, sb = 2;       // compute buf, stage buf (kt+2)
  for (int kt = 0; kt < NT1; ++kt) {
    const char* S = smem + cb * 32768;
    char* D = smem + sb * 32768;
    bf16x8 af[4], b1f[4], b3f[4];
    // ======== phase A: read A+B1 frags, stage kt+2 A, MFMA acc1 ========
#pragma unroll
    for (int mi = 0; mi < 4; mi++)
      af[mi] = *(const bf16x8*)(S + aoff + mi * 1024);
#pragma unroll
    for (int ni = 0; ni < 4; ni++)
      b1f[ni] = *(const bf16x8*)(S + 16384 + boff + ni * 1024);
    if (kt < NT1 - 2) {
      async16(ap0, D + dA0); async16(ap1, D + dA1);
      ap0 += 32; ap1 += 32;
    }
    bar_raw();
    wait_lgkm0();
    __builtin_amdgcn_s_setprio(1);
#pragma unroll
    for (int mi = 0; mi < 4; mi++)
#pragma unroll
      for (int ni = 0; ni < 4; ni++)
        acc1[mi][ni] = __builtin_amdgcn_mfma_f32_16x16x32_bf16(af[mi], b1f[ni], acc1[mi][ni], 0, 0, 0);
    __builtin_amdgcn_s_setprio(0);
    bar_raw();
    // ======== phase B: read B3 frags, stage kt+2 B, counted vmcnt, MFMA acc3 ========
#pragma unroll
    for (int ni = 0; ni < 4; ni++)
      b3f[ni] = *(const bf16x8*)(S + 24576 + boff + ni * 1024);
    if (kt < NT1 - 2) {
      async16(b1p, D + dB1); async16(b3p, D + dB3);
      b1p += 32; b3p += 32;
      wait_vm4();           // kt+1 landed; kt+2 (4 loads) stays in flight
    } else {
      wait_vm0();           // tail drain
    }
    bar_raw();
    wait_lgkm0();
    __builtin_amdgcn_s_setprio(1);
#pragma unroll
    for (int mi = 0; mi < 4; mi++)
#pragma unroll
      for (int ni = 0; ni < 4; ni++)
        acc3[mi][ni] = __builtin_amdgcn_mfma_f32_16x16x32_bf16(af[mi], b3f[ni], acc3[mi][ni], 0, 0, 0);
    __builtin_amdgcn_s_setprio(0);
    bar_raw();
    cb = (cb == 2) ? 0 : cb + 1;
    sb = (sb == 2) ? 0 : sb + 1;
  }

  // ---- epilogue: SwiGLU, masked store (C/D layout: col=lane&15, row=(lane>>4)*4+reg)
#pragma unroll
  for (int mi = 0; mi < 4; mi++) {
#pragma unroll
    for (int r = 0; r < 4; r++) {
      const int m = m0 + wm * 64 + mi * 16 + (lane >> 4) * 4 + r;
      if (m < Me) {
        unsigned short* hp = hb + (size_t)(goff + m) * HID + n0 + wn * 64 + fm;
#pragma unroll
        for (int ni = 0; ni < 4; ni++) {
          const float a = acc1[mi][ni][r];
          const float g = acc3[mi][ni][r];
          hp[ni * 16] = f2b((a / (1.0f + __expf(-a))) * g);
        }
      }
    }
  }
}

// ---------------- GEMM2: y = (h @ w2) * gate_w ----------------
// Tile 256M x 128N, BK=32, 8 waves (4M x 2N), per-wave 64x64.
// Triple-buffered LDS (3 x [A 16KB | B 8KB] = 72KB), swizzled.
// Grid 512: nb fastest (8), e (4), mb (16); same-(e,nb) stride 32 % 8 == 0.
__global__ __launch_bounds__(512, 2)
void gemm2_kernel(const unsigned short* __restrict__ hb,
                  const unsigned short* __restrict__ w2b,
                  unsigned short* __restrict__ yb,
                  const int* __restrict__ cnt, const int* __restrict__ offs,
                  const float* __restrict__ wgt) {
  const int id = blockIdx.x;
  const int nb = id & 7;
  const int e  = (id >> 3) & 3;
  const int mb = id >> 5;
  const int Me = cnt[e];
  const int m0 = mb * 256;
  if (m0 >= Me) return;
  const int n0 = nb * 128;
  const int goff = offs[e];
  const int tid = threadIdx.x, lane = tid & 63, wave = tid >> 6;
  const int wm = wave >> 1, wn = wave & 1;
  const int fm = lane & 15;

  __shared__ __align__(16) char smem[3 * 24576];

  const int pA0 = tid * 16, pA1 = 8192 + tid * 16, pB = tid * 16;
  const int lA0 = inv_swz(pA0), lA1 = inv_swz(pA1), lB = inv_swz(pB);
  const int arow0 = lA0 >> 6, ks0 = (lA0 & 63) >> 1;
  const int arow1 = lA1 >> 6, ks1 = (lA1 & 63) >> 1;
  const int brow  = lB  >> 6, ksb = (lB  & 63) >> 1;
  const unsigned short* ap0 = hb + (size_t)(goff + min(m0 + arow0, Me - 1)) * HID + ks0;
  const unsigned short* ap1 = hb + (size_t)(goff + min(m0 + arow1, Me - 1)) * HID + ks1;
  const unsigned short* bp  = w2b + ((size_t)e * DIM + n0 + brow) * HID + ksb;

  const int dA0 = wave * 1024, dA1 = 8192 + wave * 1024;
  const int dB  = 16384 + wave * 1024;

  const int X = (lane & 7) << 4;
  const int aoff = (((wm * 64 + fm) * 64) + ((lane >> 4) * 16)) ^ X;
  const int boff = (((wn * 64 + fm) * 64) + ((lane >> 4) * 16)) ^ X;

  f32x4 acc[4][4] = {};

  // prologue: stage kt0 -> buf0, kt1 -> buf1 (6 loads/thread in flight)
  {
    char* D = smem;
    async16(ap0, D + dA0); async16(ap1, D + dA1); async16(bp, D + dB);
    ap0 += 32; ap1 += 32; bp += 32;
    D = smem + 24576;
    async16(ap0, D + dA0); async16(ap1, D + dA1); async16(bp, D + dB);
    ap0 += 32; ap1 += 32; bp += 32;
  }
  wait_vm3();               // kt0 landed; kt1 (3 loads) in flight
  bar_raw();

  int cb = 0, sb = 2;
  for (int kt = 0; kt < NT2; ++kt) {
    const char* S = smem + cb * 24576;
    char* D = smem + sb * 24576;
    bf16x8 af[4], bfr[4];
    // ======== phase A: read af0-1 + all B frags, stage kt+2 A, MFMA mi0-1 ========
#pragma unroll
    for (int mi = 0; mi < 2; mi++)
      af[mi] = *(const bf16x8*)(S + aoff + mi * 1024);
#pragma unroll
    for (int ni = 0; ni < 4; ni++)
      bfr[ni] = *(const bf16x8*)(S + 16384 + boff + ni * 1024);
    if (kt < NT2 - 2) {
      async16(ap0, D + dA0); async16(ap1, D + dA1);
      ap0 += 32; ap1 += 32;
    }
    bar_raw();
    wait_lgkm0();
    __builtin_amdgcn_s_setprio(1);
#pragma unroll
    for (int mi = 0; mi < 2; mi++)
#pragma unroll
      for (int ni = 0; ni < 4; ni++)
        acc[mi][ni] = __builtin_amdgcn_mfma_f32_16x16x32_bf16(af[mi], bfr[ni], acc[mi][ni], 0, 0, 0);
    __builtin_amdgcn_s_setprio(0);
    bar_raw();
    // ======== phase B: read af2-3, stage kt+2 B, counted vmcnt, MFMA mi2-3 ========
#pragma unroll
    for (int mi = 2; mi < 4; mi++)
      af[mi] = *(const bf16x8*)(S + aoff + mi * 1024);
    if (kt < NT2 - 2) {
      async16(bp, D + dB);
      bp += 32;
      wait_vm3();           // kt+1 landed; kt+2 (3 loads) stays in flight
    } else {
      wait_vm0();           // tail drain
    }
    bar_raw();
    wait_lgkm0();
    __builtin_amdgcn_s_setprio(1);
#pragma unroll
    for (int mi = 2; mi < 4; mi++)
#pragma unroll
      for (int ni = 0; ni < 4; ni++)
        acc[mi][ni] = __builtin_amdgcn_mfma_f32_16x16x32_bf16(af[mi], bfr[ni], acc[mi][ni], 0, 0, 0);
    __builtin_amdgcn_s_setprio(0);
    bar_raw();
    cb = (cb == 2) ? 0 : cb + 1;
    sb = (sb == 2) ? 0 : sb + 1;
  }

#pragma unroll
  for (int mi = 0; mi < 4; mi++) {
#pragma unroll
    for (int r = 0; r < 4; r++) {
      const int m = m0 + wm * 64 + mi * 16 + (lane >> 4) * 4 + r;
      if (m < Me) {
        const float gwv = wgt[e * T_TOK + m];
        unsigned short* yp = yb + (size_t)(goff + m) * DIM + n0 + wn * 64 + fm;
#pragma unroll
        for (int ni = 0; ni < 4; ni++)
          yp[ni * 16] = f2b(acc[mi][ni][r] * gwv);
      }
    }
  }
}

// ---------------- combine: out[t] = y[slot0(t)] + y[slot1(t)] ----------------
__global__ void combine_kernel(const unsigned short* __restrict__ yb,
                               const int* __restrict__ code,
                               const int* __restrict__ offs,
                               float* __restrict__ out) {
  const int t = blockIdx.x;
  const int d = threadIdx.x * 4;
  const int c0 = code[t * 2 + 0];
  const int c1 = code[t * 2 + 1];
  const size_t g0 = ((size_t)(offs[c0 >> 12] + (c0 & 4095))) * DIM + d;
  const size_t g1 = ((size_t)(offs[c1 >> 12] + (c1 & 4095))) * DIM + d;
  const ushort4 y0 = *(const ushort4*)(yb + g0);
  const ushort4 y1 = *(const ushort4*)(yb + g1);
  float4 o;
  o.x = b2f(y0.x) + b2f(y1.x);
  o.y = b2f(y0.y) + b2f(y1.y);
  o.z = b2f(y0.z) + b2f(y1.z);
  o.w = b2f(y0.w) + b2f(y1.w);
  *(float4*)(out + (size_t)t * DIM + d) = o;
}

extern "C" void kernel_launch(void* const* d_in, const int* in_sizes, int n_in,
                              void* d_out, int out_size, void* d_ws, size_t ws_size,
                              hipStream_t stream) {
  (void)in_sizes; (void)n_in; (void)out_size; (void)ws_size;
  const float* x  = (const float*)d_in[0];
  const float* gw = (const float*)d_in[1];
  const float* w1 = (const float*)d_in[2];   // [E][D][H]
  const float* w2 = (const float*)d_in[3];   // [E][H][D]  (dict order: w2 before w3!)
  const float* w3 = (const float*)d_in[4];   // [E][D][H]
  float* out = (float*)d_out;
  char* ws = (char*)d_ws;

  unsigned short* xb  = (unsigned short*)(ws + 0);
  unsigned short* w1b = (unsigned short*)(ws + 8388608);
  unsigned short* yb  = (unsigned short*)(ws + 8388608);    // aliases w1b (dead after gemm1)
  unsigned short* w3b = (unsigned short*)(ws + 54525952);
  unsigned short* w2b = (unsigned short*)(ws + 100663296);
  unsigned short* hb  = (unsigned short*)(ws + 146800640);  // 8320 rows x 5632 bf16 (128 pad rows)
  int*   cnt  = (int*)(ws + 240517120);
  int*   offs = (int*)(ws + 240517152);
  int*   perm = (int*)(ws + 240517184);
  float* wgt  = (float*)(ws + 240582720);
  int*   code = (int*)(ws + 240648256);

  hipMemsetAsync(cnt, 0, EA * sizeof(int), stream);
  cvtx_kernel<<<4096, 256, 0, stream>>>(x, xb);
  gate_kernel<<<1024, 256, 0, stream>>>(x, gw, cnt, perm, wgt, code);
  offsets_kernel<<<1, 64, 0, stream>>>(cnt, offs);
  tcvt_kernel<<<dim3(88, 16, EA), 256, 0, stream>>>(w1, w1b, DIM, HID);  // -> [e][H][D]
  tcvt_kernel<<<dim3(88, 16, EA), 256, 0, stream>>>(w3, w3b, DIM, HID);  // -> [e][H][D]
  tcvt_kernel<<<dim3(16, 88, EA), 256, 0, stream>>>(w2, w2b, HID, DIM);  // -> [e][D][H]
  gemm1_kernel<<<2816, 512, 0, stream>>>(xb, w1b, w3b, hb, cnt, offs, perm);
  gemm2_kernel<<<512, 512, 0, stream>>>(hb, w2b, yb, cnt, offs, wgt);
  combine_kernel<<<4096, 256, 0, stream>>>(yb, code, offs, out);
}

// Round 5
// 945.811 us; speedup vs baseline: 1.0038x; 1.0038x over previous
//
#include <hip/hip_runtime.h>
#include <cstdint>

// MoE grouped-GEMM pipeline for MI355X (gfx950).
//   T=4096 tokens, D=1024, H=5632, experts 0..3 active (4..7 masked), top-2.
// R7 == R6 resubmit (GPU unavailable; audited: race-freedom, vmcnt ledger,
//     swizzle staging map, occupancy arithmetic -- no changes).
// R6: occupancy restructure. 128x128 tile, 256 thr (4 waves 2x2), BK=32,
//     triple-buffer (gemm1 72KB -> 2 blocks/CU; gemm2 48KB -> 3 blocks/CU),
//     ONE barrier per K-tile (reads -> stage -> lgkm0 -> MFMA -> counted vm -> bar),
//     counted vmcnt (T4, 2-iter prefetch slack), XOR swizzle (T2), setprio (T5).
//     R5 measured: 1 block/CU, Occupancy 20.8%, MfmaUtil 34.5% -> lockstep-stall bound.
// Workspace layout (bytes), total 240,681,024 (yb aliases w1b, dead after gemm1):
//   xb 0 | w1b/yb 8388608 | w3b 54525952 | w2b 100663296 | hb 146800640 (8320 rows pad)
//   cnt 240517120 | offs 240517152 | perm 240517184 | wgt 240582720 | code 240648256

#define T_TOK 4096
#define DIM   1024
#define HID   5632
#define EA    4
#define NT1   32     // gemm1 K-tiles: 1024/32
#define NT2   176    // gemm2 K-tiles: 5632/32

typedef __bf16 bf16x8 __attribute__((ext_vector_type(8)));
typedef float  f32x4  __attribute__((ext_vector_type(4)));

__device__ __forceinline__ unsigned short f2b(float f) {
  union { float f; uint32_t u; } v; v.f = f;
  uint32_t r = v.u + 0x7fffu + ((v.u >> 16) & 1u);   // RNE, matches HW cvt
  return (unsigned short)(r >> 16);
}
__device__ __forceinline__ float b2f(unsigned short u) {
  union { uint32_t u; float f; } v; v.u = ((uint32_t)u) << 16;
  return v.f;
}
// async global->LDS, 16B per lane; LDS dest = wave-uniform base + lane*16
__device__ __forceinline__ void async16(const void* g, void* l) {
  __builtin_amdgcn_global_load_lds((const __attribute__((address_space(1))) void*)g,
                                   (__attribute__((address_space(3))) void*)l,
                                   16, 0, 0);
}
// raw sync primitives: keep prefetch loads in flight across the barrier
__device__ __forceinline__ void bar_raw()   { asm volatile("s_barrier" ::: "memory"); }
__device__ __forceinline__ void wait_vm6()  { asm volatile("s_waitcnt vmcnt(6)" ::: "memory"); }
__device__ __forceinline__ void wait_vm4()  { asm volatile("s_waitcnt vmcnt(4)" ::: "memory"); }
__device__ __forceinline__ void wait_vm0()  { asm volatile("s_waitcnt vmcnt(0)" ::: "memory"); }
__device__ __forceinline__ void wait_lgkm0(){ asm volatile("s_waitcnt lgkmcnt(0)" ::: "memory"); }

// LDS tile swizzle: logical byte L in a [rows][32 bf16] region (64B rows),
// phys = L ^ ((row&7)<<4)  with row = L>>6, i.e. p4^=L6, p5^=L7, p6^=L8.
// Read side: frag offset ^= (lane&7)<<4 (row bits 0-2 == fm bits 0-2).
// Stage side uses the inverse (phys slot -> logical element); 16B-block-preserving.
__device__ __forceinline__ int inv_swz(int p) {
  const int b6 = (p >> 6) & 1, b7 = (p >> 7) & 1, b8 = (p >> 8) & 1;
  return p ^ (((b6 ^ b8) << 4) | (b7 << 5) | (b8 << 6));
}

// ---------------- x fp32 -> bf16 ----------------
__global__ void cvtx_kernel(const float* __restrict__ x, unsigned short* __restrict__ xb) {
  const int i = blockIdx.x * blockDim.x + threadIdx.x;
  const float4 v = ((const float4*)x)[i];
  ushort4 o;
  o.x = f2b(v.x); o.y = f2b(v.y); o.z = f2b(v.z); o.w = f2b(v.w);
  ((ushort4*)xb)[i] = o;
}

// ---------------- gating: fp32 logits (experts 0..3), top-2, route ----------------
__global__ void gate_kernel(const float* __restrict__ x, const float* __restrict__ gw,
                            int* __restrict__ cnt, int* __restrict__ perm,
                            float* __restrict__ wgt, int* __restrict__ code) {
  const int lane = threadIdx.x & 63;
  const int wave = threadIdx.x >> 6;
  const int t = blockIdx.x * 4 + wave;          // one wave per token
  const float4* xv = (const float4*)(x + (size_t)t * DIM);
  const float4* g0 = (const float4*)gw;
  const float4* g1 = (const float4*)(gw + DIM);
  const float4* g2 = (const float4*)(gw + 2 * DIM);
  const float4* g3 = (const float4*)(gw + 3 * DIM);
  float a0 = 0.f, a1 = 0.f, a2 = 0.f, a3 = 0.f;
#pragma unroll
  for (int i = 0; i < 4; i++) {
    const int idx = i * 64 + lane;
    const float4 v = xv[idx];
    float4 w;
    w = g0[idx]; a0 += v.x*w.x + v.y*w.y + v.z*w.z + v.w*w.w;
    w = g1[idx]; a1 += v.x*w.x + v.y*w.y + v.z*w.z + v.w*w.w;
    w = g2[idx]; a2 += v.x*w.x + v.y*w.y + v.z*w.z + v.w*w.w;
    w = g3[idx]; a3 += v.x*w.x + v.y*w.y + v.z*w.z + v.w*w.w;
  }
#pragma unroll
  for (int off = 32; off > 0; off >>= 1) {
    a0 += __shfl_xor(a0, off);
    a1 += __shfl_xor(a1, off);
    a2 += __shfl_xor(a2, off);
    a3 += __shfl_xor(a3, off);
  }
  if (lane == 0) {
    float l[4] = {a0, a1, a2, a3};
    int a = 0;
#pragma unroll
    for (int e = 1; e < 4; e++) if (l[e] > l[a]) a = e;   // ties -> lower index (jax top_k)
    int b = (a == 0) ? 1 : 0;
#pragma unroll
    for (int e = 0; e < 4; e++) if (e != a && l[e] > l[b]) b = e;
    // softmax(top2) renormalized == sigmoid of logit gap
    const float wa = 1.0f / (1.0f + __expf(l[b] - l[a]));
    const float wb = 1.0f - wa;
    const int pa = atomicAdd(&cnt[a], 1);
    const int pb = atomicAdd(&cnt[b], 1);
    perm[a * T_TOK + pa] = t;  wgt[a * T_TOK + pa] = wa;  code[t * 2 + 0] = a * T_TOK + pa;
    perm[b * T_TOK + pb] = t;  wgt[b * T_TOK + pb] = wb;  code[t * 2 + 1] = b * T_TOK + pb;
  }
}

__global__ void offsets_kernel(const int* __restrict__ cnt, int* __restrict__ offs) {
  if (threadIdx.x == 0 && blockIdx.x == 0) {
    int s = 0;
#pragma unroll
    for (int e = 0; e < EA; e++) { offs[e] = s; s += cnt[e]; }
  }
}

// ---------------- per-expert transpose + fp32->bf16: in [R][C] -> out [C][R] ----------------
__global__ void tcvt_kernel(const float* __restrict__ in, unsigned short* __restrict__ out,
                            int R, int C) {
  __shared__ float tile[64][65];
  const size_t es = (size_t)R * C;
  const float* ip = in + (size_t)blockIdx.z * es;
  unsigned short* op = out + (size_t)blockIdx.z * es;
  const int bc = blockIdx.x * 64;
  const int br = blockIdx.y * 64;
  const int tr = threadIdx.x >> 4;
  const int tc = (threadIdx.x & 15) * 4;
#pragma unroll
  for (int i = 0; i < 4; i++) {
    const float4 v = *(const float4*)(ip + (size_t)(br + tr + i * 16) * C + bc + tc);
    tile[tr + i * 16][tc + 0] = v.x;
    tile[tr + i * 16][tc + 1] = v.y;
    tile[tr + i * 16][tc + 2] = v.z;
    tile[tr + i * 16][tc + 3] = v.w;
  }
  __syncthreads();
#pragma unroll
  for (int i = 0; i < 4; i++) {
    const int n = bc + tr + i * 16;
    ushort4 o;
    o.x = f2b(tile[tc + 0][tr + i * 16]);
    o.y = f2b(tile[tc + 1][tr + i * 16]);
    o.z = f2b(tile[tc + 2][tr + i * 16]);
    o.w = f2b(tile[tc + 3][tr + i * 16]);
    *(ushort4*)(op + (size_t)n * R + br + tc) = o;
  }
}

// ---------------- GEMM1: h = silu(x@w1) * (x@w3) ----------------
// Tile 128M x 128N, BK=32, 4 waves (2M x 2N), per-wave 64x64 per matrix.
// Triple-buffered LDS: buf = [A 8KB | B1 8KB | B3 8KB] = 24KB, x3 = 72KB -> 2 blocks/CU.
// One barrier per K-tile; counted vmcnt(6) (2-iter prefetch slack).
// Grid 5632: nb fastest (44), e (4), mb (32); same-(e,nb) stride 176 % 8 == 0.
__global__ __launch_bounds__(256, 2)
void gemm1_kernel(const unsigned short* __restrict__ xb,
                  const unsigned short* __restrict__ w1b,
                  const unsigned short* __restrict__ w3b,
                  unsigned short* __restrict__ hb,
                  const int* __restrict__ cnt, const int* __restrict__ offs,
                  const int* __restrict__ perm) {
  const int id = blockIdx.x;
  const int nb = id % 44;
  const int e  = (id / 44) % 4;
  const int mb = id / 176;              // 0..31
  const int Me = cnt[e];
  const int m0 = mb * 128;
  if (m0 >= Me) return;
  const int n0 = nb * 128;
  const int goff = offs[e];
  const int tid = threadIdx.x, lane = tid & 63, wave = tid >> 6;
  const int wm = wave >> 1, wn = wave & 1;
  const int fm = lane & 15;

  __shared__ __align__(16) char smem[3 * 24576];

  // ---- staging: per wave 6 chunks of 1KB (A0,A1,B1a,B1b,B3a,B3b).
  // phys region-offset this thread writes = t16 (chunk a) / 4096+t16 (chunk b);
  // logical source element = inv_swz of that (swizzle only touches bits 4-8).
  const int t16 = tid * 16;
  const int l0 = inv_swz(t16);
  const int row0 = l0 >> 6;             // 0..63
  const int row1 = row0 + 64;           // inv_swz(4096+t16) = 4096 + inv_swz(t16)
  const int ks   = (l0 & 63) >> 1;      // shorts within row
  const int tok0 = perm[e * T_TOK + min(m0 + row0, Me - 1)];
  const int tok1 = perm[e * T_TOK + min(m0 + row1, Me - 1)];
  const unsigned short* ap0  = xb + (size_t)tok0 * DIM + ks;
  const unsigned short* ap1  = xb + (size_t)tok1 * DIM + ks;
  const unsigned short* b1p0 = w1b + ((size_t)e * HID + n0 + row0) * DIM + ks;
  const unsigned short* b1p1 = w1b + ((size_t)e * HID + n0 + row1) * DIM + ks;
  const unsigned short* b3p0 = w3b + ((size_t)e * HID + n0 + row0) * DIM + ks;
  const unsigned short* b3p1 = w3b + ((size_t)e * HID + n0 + row1) * DIM + ks;

  // ---- LDS stage dests (wave-uniform; HW adds lane*16)
  const int dA0 = wave * 1024,          dA1 = 4096  + wave * 1024;
  const int dB10 = 8192 + wave * 1024,  dB11 = 12288 + wave * 1024;
  const int dB30 = 16384 + wave * 1024, dB31 = 20480 + wave * 1024;

  // ---- swizzled frag read offsets (row = wm*64 + mi*16 + fm; row&7 == lane&7)
  const int X = (lane & 7) << 4;
  const int aoff = (((wm * 64 + fm) * 64) + ((lane >> 4) * 16)) ^ X;
  const int boff = (((wn * 64 + fm) * 64) + ((lane >> 4) * 16)) ^ X;

  f32x4 acc1[4][4] = {};
  f32x4 acc3[4][4] = {};

#define G1_STAGE(D) do { \
    async16(ap0,  (D) + dA0);  async16(ap1,  (D) + dA1);  \
    async16(b1p0, (D) + dB10); async16(b1p1, (D) + dB11); \
    async16(b3p0, (D) + dB30); async16(b3p1, (D) + dB31); \
    ap0 += 32; ap1 += 32; b1p0 += 32; b1p1 += 32; b3p0 += 32; b3p1 += 32; \
  } while (0)

  // ---- prologue: stage kt0 -> buf0, kt1 -> buf1 (12 loads in flight)
  G1_STAGE(smem);
  G1_STAGE(smem + 24576);
  wait_vm6();               // kt0 landed; kt1 (6 loads) still in flight
  bar_raw();

  int cb = 0, sb = 2;       // compute buf (kt), stage buf (kt+2)
  for (int kt = 0; kt < NT1; ++kt) {
    const char* S = smem + cb * 24576;
    char* D = smem + sb * 24576;
    bf16x8 af[4], b1f[4], b3f[4];
#pragma unroll
    for (int mi = 0; mi < 4; mi++)
      af[mi] = *(const bf16x8*)(S + aoff + mi * 1024);
#pragma unroll
    for (int ni = 0; ni < 4; ni++) {
      b1f[ni] = *(const bf16x8*)(S + 8192  + boff + ni * 1024);
      b3f[ni] = *(const bf16x8*)(S + 16384 + boff + ni * 1024);
    }
    if (kt < NT1 - 2) G1_STAGE(D);
    wait_lgkm0();
    __builtin_amdgcn_s_setprio(1);
#pragma unroll
    for (int mi = 0; mi < 4; mi++)
#pragma unroll
      for (int ni = 0; ni < 4; ni++) {
        acc1[mi][ni] = __builtin_amdgcn_mfma_f32_16x16x32_bf16(af[mi], b1f[ni], acc1[mi][ni], 0, 0, 0);
        acc3[mi][ni] = __builtin_amdgcn_mfma_f32_16x16x32_bf16(af[mi], b3f[ni], acc3[mi][ni], 0, 0, 0);
      }
    __builtin_amdgcn_s_setprio(0);
    if (kt < NT1 - 2) wait_vm6(); else wait_vm0();   // kt+1 landed; kt+2 in flight
    bar_raw();
    cb = (cb == 2) ? 0 : cb + 1;
    sb = (sb == 2) ? 0 : sb + 1;
  }
#undef G1_STAGE

  // ---- epilogue: SwiGLU, masked store (C/D layout: col=lane&15, row=(lane>>4)*4+reg)
#pragma unroll
  for (int mi = 0; mi < 4; mi++) {
#pragma unroll
    for (int r = 0; r < 4; r++) {
      const int m = m0 + wm * 64 + mi * 16 + (lane >> 4) * 4 + r;
      if (m < Me) {
        unsigned short* hp = hb + (size_t)(goff + m) * HID + n0 + wn * 64 + fm;
#pragma unroll
        for (int ni = 0; ni < 4; ni++) {
          const float a = acc1[mi][ni][r];
          const float g = acc3[mi][ni][r];
          hp[ni * 16] = f2b((a / (1.0f + __expf(-a))) * g);
        }
      }
    }
  }
}

// ---------------- GEMM2: y = (h @ w2) * gate_w ----------------
// Tile 128M x 128N, BK=32, 4 waves (2M x 2N), per-wave 64x64.
// Triple-buffered LDS: buf = [A 8KB | B 8KB] = 16KB, x3 = 48KB -> 3 blocks/CU.
// One barrier per K-tile; counted vmcnt(4).
// Grid 1024: nb fastest (8), e (4), mb (32); same-(e,nb) stride 32 % 8 == 0.
__global__ __launch_bounds__(256, 3)
void gemm2_kernel(const unsigned short* __restrict__ hb,
                  const unsigned short* __restrict__ w2b,
                  unsigned short* __restrict__ yb,
                  const int* __restrict__ cnt, const int* __restrict__ offs,
                  const float* __restrict__ wgt) {
  const int id = blockIdx.x;
  const int nb = id & 7;
  const int e  = (id >> 3) & 3;
  const int mb = id >> 5;               // 0..31
  const int Me = cnt[e];
  const int m0 = mb * 128;
  if (m0 >= Me) return;
  const int n0 = nb * 128;
  const int goff = offs[e];
  const int tid = threadIdx.x, lane = tid & 63, wave = tid >> 6;
  const int wm = wave >> 1, wn = wave & 1;
  const int fm = lane & 15;

  __shared__ __align__(16) char smem[3 * 16384];

  const int t16 = tid * 16;
  const int l0 = inv_swz(t16);
  const int row0 = l0 >> 6;
  const int row1 = row0 + 64;
  const int ks   = (l0 & 63) >> 1;
  const unsigned short* ap0 = hb + (size_t)(goff + min(m0 + row0, Me - 1)) * HID + ks;
  const unsigned short* ap1 = hb + (size_t)(goff + min(m0 + row1, Me - 1)) * HID + ks;
  const unsigned short* bp0 = w2b + ((size_t)e * DIM + n0 + row0) * HID + ks;
  const unsigned short* bp1 = w2b + ((size_t)e * DIM + n0 + row1) * HID + ks;

  const int dA0 = wave * 1024,         dA1 = 4096  + wave * 1024;
  const int dB0 = 8192 + wave * 1024,  dB1 = 12288 + wave * 1024;

  const int X = (lane & 7) << 4;
  const int aoff = (((wm * 64 + fm) * 64) + ((lane >> 4) * 16)) ^ X;
  const int boff = (((wn * 64 + fm) * 64) + ((lane >> 4) * 16)) ^ X;

  f32x4 acc[4][4] = {};

#define G2_STAGE(D) do { \
    async16(ap0, (D) + dA0); async16(ap1, (D) + dA1); \
    async16(bp0, (D) + dB0); async16(bp1, (D) + dB1); \
    ap0 += 32; ap1 += 32; bp0 += 32; bp1 += 32; \
  } while (0)

  G2_STAGE(smem);
  G2_STAGE(smem + 16384);
  wait_vm4();               // kt0 landed; kt1 (4 loads) in flight
  bar_raw();

  int cb = 0, sb = 2;
  for (int kt = 0; kt < NT2; ++kt) {
    const char* S = smem + cb * 16384;
    char* D = smem + sb * 16384;
    bf16x8 af[4], bfr[4];
#pragma unroll
    for (int mi = 0; mi < 4; mi++)
      af[mi] = *(const bf16x8*)(S + aoff + mi * 1024);
#pragma unroll
    for (int ni = 0; ni < 4; ni++)
      bfr[ni] = *(const bf16x8*)(S + 8192 + boff + ni * 1024);
    if (kt < NT2 - 2) G2_STAGE(D);
    wait_lgkm0();
    __builtin_amdgcn_s_setprio(1);
#pragma unroll
    for (int mi = 0; mi < 4; mi++)
#pragma unroll
      for (int ni = 0; ni < 4; ni++)
        acc[mi][ni] = __builtin_amdgcn_mfma_f32_16x16x32_bf16(af[mi], bfr[ni], acc[mi][ni], 0, 0, 0);
    __builtin_amdgcn_s_setprio(0);
    if (kt < NT2 - 2) wait_vm4(); else wait_vm0();
    bar_raw();
    cb = (cb == 2) ? 0 : cb + 1;
    sb = (sb == 2) ? 0 : sb + 1;
  }
#undef G2_STAGE

#pragma unroll
  for (int mi = 0; mi < 4; mi++) {
#pragma unroll
    for (int r = 0; r < 4; r++) {
      const int m = m0 + wm * 64 + mi * 16 + (lane >> 4) * 4 + r;
      if (m < Me) {
        const float gwv = wgt[e * T_TOK + m];
        unsigned short* yp = yb + (size_t)(goff + m) * DIM + n0 + wn * 64 + fm;
#pragma unroll
        for (int ni = 0; ni < 4; ni++)
          yp[ni * 16] = f2b(acc[mi][ni][r] * gwv);
      }
    }
  }
}

// ---------------- combine: out[t] = y[slot0(t)] + y[slot1(t)] ----------------
__global__ void combine_kernel(const unsigned short* __restrict__ yb,
                               const int* __restrict__ code,
                               const int* __restrict__ offs,
                               float* __restrict__ out) {
  const int t = blockIdx.x;
  const int d = threadIdx.x * 4;
  const int c0 = code[t * 2 + 0];
  const int c1 = code[t * 2 + 1];
  const size_t g0 = ((size_t)(offs[c0 >> 12] + (c0 & 4095))) * DIM + d;
  const size_t g1 = ((size_t)(offs[c1 >> 12] + (c1 & 4095))) * DIM + d;
  const ushort4 y0 = *(const ushort4*)(yb + g0);
  const ushort4 y1 = *(const ushort4*)(yb + g1);
  float4 o;
  o.x = b2f(y0.x) + b2f(y1.x);
  o.y = b2f(y0.y) + b2f(y1.y);
  o.z = b2f(y0.z) + b2f(y1.z);
  o.w = b2f(y0.w) + b2f(y1.w);
  *(float4*)(out + (size_t)t * DIM + d) = o;
}

extern "C" void kernel_launch(void* const* d_in, const int* in_sizes, int n_in,
                              void* d_out, int out_size, void* d_ws, size_t ws_size,
                              hipStream_t stream) {
  (void)in_sizes; (void)n_in; (void)out_size; (void)ws_size;
  const float* x  = (const float*)d_in[0];
  const float* gw = (const float*)d_in[1];
  const float* w1 = (const float*)d_in[2];   // [E][D][H]
  const float* w2 = (const float*)d_in[3];   // [E][H][D]  (dict order: w2 before w3!)
  const float* w3 = (const float*)d_in[4];   // [E][D][H]
  float* out = (float*)d_out;
  char* ws = (char*)d_ws;

  unsigned short* xb  = (unsigned short*)(ws + 0);
  unsigned short* w1b = (unsigned short*)(ws + 8388608);
  unsigned short* yb  = (unsigned short*)(ws + 8388608);    // aliases w1b (dead after gemm1)
  unsigned short* w3b = (unsigned short*)(ws + 54525952);
  unsigned short* w2b = (unsigned short*)(ws + 100663296);
  unsigned short* hb  = (unsigned short*)(ws + 146800640);  // 8320 rows x 5632 bf16 (128 pad rows)
  int*   cnt  = (int*)(ws + 240517120);
  int*   offs = (int*)(ws + 240517152);
  int*   perm = (int*)(ws + 240517184);
  float* wgt  = (float*)(ws + 240582720);
  int*   code = (int*)(ws + 240648256);

  hipMemsetAsync(cnt, 0, EA * sizeof(int), stream);
  cvtx_kernel<<<4096, 256, 0, stream>>>(x, xb);
  gate_kernel<<<1024, 256, 0, stream>>>(x, gw, cnt, perm, wgt, code);
  offsets_kernel<<<1, 64, 0, stream>>>(cnt, offs);
  tcvt_kernel<<<dim3(88, 16, EA), 256, 0, stream>>>(w1, w1b, DIM, HID);  // -> [e][H][D]
  tcvt_kernel<<<dim3(88, 16, EA), 256, 0, stream>>>(w3, w3b, DIM, HID);  // -> [e][H][D]
  tcvt_kernel<<<dim3(16, 88, EA), 256, 0, stream>>>(w2, w2b, HID, DIM);  // -> [e][D][H]
  gemm1_kernel<<<5632, 256, 0, stream>>>(xb, w1b, w3b, hb, cnt, offs, perm);
  gemm2_kernel<<<1024, 256, 0, stream>>>(hb, w2b, yb, cnt, offs, wgt);
  combine_kernel<<<4096, 256, 0, stream>>>(yb, code, offs, out);
}